// Round 5
// baseline (3354.934 us; speedup 1.0000x reference)
//
#include <hip/hip_runtime.h>

// ---------------------------------------------------------------------------
// Elman RNN (B=64, T=512, H=512, V=50257, O=4), faithful to the JAX reference
// (including softmax-before-CE bug).
//
//   K3 rnn_steps (the 82% kernel): 64 WGs (1 batch row / CU), 256 threads,
//   thread l owns output cols l and l+256. W_h residency:
//     k in [0,384): 2x192 dwords/thread in REGISTERS — col l's half pinned to
//       AGPRs via chunk-wise "+a" asm (round-3 lesson: "+v" alone let the
//       allocator place them in scratch -> L2 refetch each step, 977us),
//       col l+256's half in arch VGPRs ("+v" pinned).
//     k in [384,512): 128 KB XOR-swizzled LDS, shared.
//   h broadcast: uniform ds_read_b128 (true broadcast: 16 B bus cost), each
//   16B read feeds 8 dot2 (2 cols). One __syncthreads per step.
// ---------------------------------------------------------------------------

typedef _Float16 f16;
typedef _Float16 half2_t __attribute__((ext_vector_type(2)));
typedef _Float16 half8_t __attribute__((ext_vector_type(8)));
typedef float f32x4 __attribute__((ext_vector_type(4)));
typedef unsigned int u32x4 __attribute__((ext_vector_type(4)));

#define HDIM 512
#define BATCH 64
#define TSTEPS 512
#define OUTC 4

__device__ __forceinline__ float dot2f(unsigned int h, unsigned int w, float acc) {
#if __has_builtin(__builtin_amdgcn_fdot2)
  return __builtin_amdgcn_fdot2(__builtin_bit_cast(half2_t, h),
                                __builtin_bit_cast(half2_t, w), acc, false);
#else
  half2_t a = __builtin_bit_cast(half2_t, h);
  half2_t b = __builtin_bit_cast(half2_t, w);
  return acc + (float)a.x * (float)b.x + (float)a.y * (float)b.y;
#endif
}

// ---- K1: fp32 -> f16 weight conversion -------------------------------------
__global__ void convert_w(const float* __restrict__ Win, const float* __restrict__ Wh,
                          f16* __restrict__ wif, f16* __restrict__ whf) {
  int i = blockIdx.x * 256 + threadIdx.x;
  if (i < HDIM * HDIM) {
    wif[i] = (f16)Win[i];
    whf[i] = (f16)Wh[i];
  }
}

// ---- K1b: gather+convert embeddings once -----------------------------------
__global__ __launch_bounds__(256) void embed_f16(const int* __restrict__ ids,
                                                 const float* __restrict__ emb,
                                                 f16* __restrict__ xh) {
  int gid = blockIdx.x * 256 + threadIdx.x;   // 32768 rows x 128 float4-lanes
  int r = gid >> 7;                           // token row = t*64 + b
  int lane = gid & 127;
  int id = ids[(r & 63) * TSTEPS + (r >> 6)]; // ids[b][t], [B][T] layout
  float4 a = *(const float4*)(emb + id * HDIM + lane * 4);
  half2_t lo, hi;
  lo.x = (f16)a.x; lo.y = (f16)a.y;
  hi.x = (f16)a.z; hi.y = (f16)a.w;
  half2_t* dst = (half2_t*)(xh + r * HDIM + lane * 4);
  dst[0] = lo;
  dst[1] = hi;
}

// ---- K2: pre[t*64+b][j] = xh @ W_in^T + b_h  (MFMA f16) --------------------
__global__ __launch_bounds__(256) void gemm_pre(const f16* __restrict__ xh,
                                                const f16* __restrict__ wif,
                                                const float* __restrict__ bh,
                                                f16* __restrict__ preh) {
  __shared__ __align__(16) f16 Al[64][40];
  __shared__ __align__(16) f16 Bl[64][40];

  const int tid = threadIdx.x;
  const int rb = blockIdx.x;
  const int nb = blockIdx.y;
  const int w = tid >> 6;
  const int l = tid & 63;

  f32x4 acc[4] = {};
  const int srow = tid >> 2;
  const int quad = tid & 3;

  for (int k0 = 0; k0 < HDIM; k0 += 32) {
    *(u32x4*)&Al[srow][quad * 8] =
        *(const u32x4*)(xh + (rb * 64 + srow) * HDIM + k0 + quad * 8);
    *(u32x4*)&Bl[srow][quad * 8] =
        *(const u32x4*)(wif + (nb * 64 + srow) * HDIM + k0 + quad * 8);
    __syncthreads();

    half8_t af = *(const half8_t*)&Al[w * 16 + (l & 15)][(l >> 4) * 8];
#pragma unroll
    for (int nt = 0; nt < 4; ++nt) {
      half8_t bf = *(const half8_t*)&Bl[nt * 16 + (l & 15)][(l >> 4) * 8];
      acc[nt] = __builtin_amdgcn_mfma_f32_16x16x32_f16(af, bf, acc[nt], 0, 0, 0);
    }
    __syncthreads();
  }

  // epilogue: C/D mapping col=lane&15, row=(lane>>4)*4+i  (m89-verified)
#pragma unroll
  for (int nt = 0; nt < 4; ++nt) {
#pragma unroll
    for (int i = 0; i < 4; ++i) {
      int r = rb * 64 + w * 16 + (l >> 4) * 4 + i;
      int c = nb * 64 + nt * 16 + (l & 15);
      preh[r * HDIM + c] = (f16)(acc[nt][i] + bh[c]);
    }
  }
}

// ---- K3: the 512-step recurrence, one batch row per CU ---------------------
// 256 threads; thread l computes output cols l and l+256.
__global__ __launch_bounds__(256, 1) void rnn_steps(const f16* __restrict__ preh,
                                                    const f16* __restrict__ whf,
                                                    float* __restrict__ hT) {
  __shared__ __align__(16) u32x4 wlds[HDIM * 16];          // 128 KB: k in [384,512)
  __shared__ __align__(16) unsigned int hb[2][HDIM / 2];   // h as f16 pairs, dbuf

  const int l = threadIdx.x;   // 0..255
  const int b = blockIdx.x;    // batch row

  // Swizzled LDS weights: row j, 16B granule c stored at (c ^ (j&15)).
  for (int q = 0; q < 32; ++q) {
    int idx = q * 256 + l;          // 8192 granules over 512 rows x 16
    int row = idx >> 4, c = idx & 15;
    u32x4 v = *(const u32x4*)(whf + row * HDIM + 384 + c * 8);
    wlds[row * 16 + (c ^ (row & 15))] = v;
  }

  // Register-resident weights, k in [0,384):
  //   wa[192] <- W_h[l][0:384)      pinned to AGPRs chunk-wise at load
  //   wv[192] <- W_h[l+256][0:384)  pinned to arch VGPRs
  unsigned int wa[192], wv[192];
  {
    const u32x4* ra = (const u32x4*)(whf + l * HDIM);
#pragma unroll
    for (int c = 0; c < 48; ++c) {
      u32x4 v = ra[c];
      unsigned int x0 = v[0], x1 = v[1], x2 = v[2], x3 = v[3];
      // pin THIS chunk to AGPRs immediately so peak arch-VGPR pressure during
      // the load phase stays bounded (384 simultaneously VGPR-live values
      // would exceed the 256 arch cap and force the round-2 scratch spill).
      asm volatile("" : "+a"(x0), "+a"(x1), "+a"(x2), "+a"(x3));
      wa[4 * c + 0] = x0; wa[4 * c + 1] = x1;
      wa[4 * c + 2] = x2; wa[4 * c + 3] = x3;
    }
    const u32x4* rv = (const u32x4*)(whf + (l + 256) * HDIM);
#pragma unroll
    for (int c = 0; c < 48; ++c) {
      u32x4 v = rv[c];
      wv[4 * c + 0] = v[0]; wv[4 * c + 1] = v[1];
      wv[4 * c + 2] = v[2]; wv[4 * c + 3] = v[3];
    }
  }
#pragma unroll
  for (int c = 0; c < 192; c += 4)
    asm volatile("" : "+v"(wv[c]), "+v"(wv[c + 1]), "+v"(wv[c + 2]), "+v"(wv[c + 3]));
#pragma unroll
  for (int c = 0; c < 192; c += 4)
    asm volatile("" : "+a"(wa[c]), "+a"(wa[c + 1]), "+a"(wa[c + 2]), "+a"(wa[c + 3]));

  hb[0][l] = 0u;  // h0 = 0 (256 u32 entries, one per thread)
  __syncthreads();

  float pre0 = (float)preh[b * HDIM + l];
  float pre1 = (float)preh[b * HDIM + l + 256];
  const u32x4* wl0 = &wlds[l * 16];
  const u32x4* wl1 = &wlds[(l + 256) * 16];
  const int sw = l & 15;  // (l+256)&15 == l&15

  for (int t = 0; t < TSTEPS; ++t) {
    float pre0n = 0.f, pre1n = 0.f;
    if (t < TSTEPS - 1) {
      pre0n = (float)preh[((t + 1) * BATCH + b) * HDIM + l];
      pre1n = (float)preh[((t + 1) * BATCH + b) * HDIM + l + 256];
    }

    const u32x4* hp = (const u32x4*)hb[t & 1];
    float a0 = pre0, a1 = pre1;
#pragma unroll
    for (int c = 0; c < 48; ++c) {      // k in [0,384): register weights
      u32x4 h4 = hp[c];                 // uniform-address broadcast (16B bus)
      a0 = dot2f(h4[0], wa[4 * c + 0], a0);
      a0 = dot2f(h4[1], wa[4 * c + 1], a0);
      a0 = dot2f(h4[2], wa[4 * c + 2], a0);
      a0 = dot2f(h4[3], wa[4 * c + 3], a0);
      a1 = dot2f(h4[0], wv[4 * c + 0], a1);
      a1 = dot2f(h4[1], wv[4 * c + 1], a1);
      a1 = dot2f(h4[2], wv[4 * c + 2], a1);
      a1 = dot2f(h4[3], wv[4 * c + 3], a1);
    }
#pragma unroll
    for (int c = 0; c < 16; ++c) {      // k in [384,512): LDS weights
      u32x4 h4 = hp[48 + c];
      u32x4 w0 = wl0[c ^ sw];
      u32x4 w1 = wl1[c ^ sw];
      a0 = dot2f(h4[0], w0[0], a0);
      a0 = dot2f(h4[1], w0[1], a0);
      a0 = dot2f(h4[2], w0[2], a0);
      a0 = dot2f(h4[3], w0[3], a0);
      a1 = dot2f(h4[0], w1[0], a1);
      a1 = dot2f(h4[1], w1[1], a1);
      a1 = dot2f(h4[2], w1[2], a1);
      a1 = dot2f(h4[3], w1[3], a1);
    }
    a0 = fmaxf(a0, 0.f);
    a1 = fmaxf(a1, 0.f);
    f16* nb = (f16*)hb[(t + 1) & 1];
    nb[l] = (f16)a0;
    nb[l + 256] = (f16)a1;
    if (t == TSTEPS - 1) {
      hT[b * HDIM + l] = a0;
      hT[b * HDIM + l + 256] = a1;
    }
    pre0 = pre0n;
    pre1 = pre1n;
    __syncthreads();   // one barrier/step
  }
}

// ---- K4: logits + softmax + log_softmax + NLL ------------------------------
__global__ void tail_kernel(const float* __restrict__ hT, const float* __restrict__ Wout,
                            const float* __restrict__ bout, const int* __restrict__ labels,
                            float* __restrict__ out) {
  __shared__ float lred[BATCH];
  const int b = threadIdx.x;  // 64 threads, 1 wave
  const float4* hr = (const float4*)(hT + b * HDIM);
  const float4* w0 = (const float4*)(Wout + 0 * HDIM);
  const float4* w1 = (const float4*)(Wout + 1 * HDIM);
  const float4* w2 = (const float4*)(Wout + 2 * HDIM);
  const float4* w3 = (const float4*)(Wout + 3 * HDIM);
  float z0 = bout[0], z1 = bout[1], z2 = bout[2], z3 = bout[3];
#pragma unroll 4
  for (int k = 0; k < HDIM / 4; ++k) {
    float4 h = hr[k];
    float4 a = w0[k], c = w1[k], d = w2[k], e = w3[k];
    z0 += h.x * a.x + h.y * a.y + h.z * a.z + h.w * a.w;
    z1 += h.x * c.x + h.y * c.y + h.z * c.z + h.w * c.w;
    z2 += h.x * d.x + h.y * d.y + h.z * d.z + h.w * d.w;
    z3 += h.x * e.x + h.y * e.y + h.z * e.z + h.w * e.w;
  }
  float m = fmaxf(fmaxf(z0, z1), fmaxf(z2, z3));
  float e0 = __expf(z0 - m), e1 = __expf(z1 - m), e2 = __expf(z2 - m), e3 = __expf(z3 - m);
  float se = e0 + e1 + e2 + e3;
  float p0 = e0 / se, p1 = e1 / se, p2 = e2 / se, p3 = e3 / se;
  float m2 = fmaxf(fmaxf(p0, p1), fmaxf(p2, p3));
  float s2 = __expf(p0 - m2) + __expf(p1 - m2) + __expf(p2 - m2) + __expf(p3 - m2);
  float lse = m2 + __logf(s2);
  int lab = labels[b];
  float pl = (lab == 0) ? p0 : (lab == 1) ? p1 : (lab == 2) ? p2 : p3;
  lred[b] = pl - lse;
  out[1 + b * 4 + 0] = p0;
  out[1 + b * 4 + 1] = p1;
  out[1 + b * 4 + 2] = p2;
  out[1 + b * 4 + 3] = p3;
  __syncthreads();
  if (b == 0) {
    float s = 0.f;
#pragma unroll
    for (int i = 0; i < BATCH; ++i) s += lred[i];
    out[0] = -s / (float)BATCH;
  }
}

// ---------------------------------------------------------------------------
extern "C" void kernel_launch(void* const* d_in, const int* in_sizes, int n_in,
                              void* d_out, int out_size, void* d_ws, size_t ws_size,
                              hipStream_t stream) {
  const int* ids = (const int*)d_in[0];
  const int* labels = (const int*)d_in[1];
  const float* emb = (const float*)d_in[2];
  const float* Win = (const float*)d_in[3];
  const float* Wh = (const float*)d_in[4];
  const float* bh = (const float*)d_in[5];
  const float* Wout = (const float*)d_in[6];
  const float* bout = (const float*)d_in[7];
  float* out = (float*)d_out;

  // ws layout: whf 512K | wif 512K | preh 32M | xh 32M | hT 128K  (~66 MB)
  char* ws = (char*)d_ws;
  f16* whf = (f16*)ws;
  f16* wif = (f16*)(ws + (512 << 10));
  f16* preh = (f16*)(ws + (1 << 20));
  f16* xh = (f16*)(ws + (1 << 20) + (32 << 20));
  float* hT = (float*)(ws + (1 << 20) + (64 << 20));

  convert_w<<<dim3(1024), dim3(256), 0, stream>>>(Win, Wh, wif, whf);
  embed_f16<<<dim3((BATCH * TSTEPS * 128) / 256), dim3(256), 0, stream>>>(ids, emb, xh);
  gemm_pre<<<dim3(512, 8), dim3(256), 0, stream>>>(xh, wif, bh, preh);
  rnn_steps<<<dim3(64), dim3(256), 0, stream>>>(preh, whf, hT);
  tail_kernel<<<dim3(1), dim3(64), 0, stream>>>(hT, Wout, bout, labels, out);
}

// Round 6
// 1594.264 us; speedup vs baseline: 2.1044x; 2.1044x over previous
//
#include <hip/hip_runtime.h>

// ---------------------------------------------------------------------------
// Elman RNN (B=64, T=512, H=512, V=50257, O=4), faithful to the JAX reference
// (including softmax-before-CE bug).
//
//   K3 rnn_steps: 64 WGs (1 batch row / CU), 512 threads, thread j = col j.
//   W_h residency: k in [0,384) -> 192 dwords/thread in arch VGPRs.
//     Round-1/3/5 forensics: allocator budget is block-shape dependent.
//     8-wave blocks got capped ~116-128 (heuristic targets 2 blocks/CU,
//     ignoring the 130KB-LDS 1-block limit) -> 192-dword ask remat'd/spilled
//     to scratch->L2 (~4580 cy/step); 4-wave block got 256 arch but the
//     384-dword 2-col ask spilled (r5: WRITE 9MB, 3.2x slower).
//     Fix: amdgpu_waves_per_eu(2,2) pins the occupancy target at exactly
//     2 waves/EU (= this kernel's only feasible shape) -> 256-reg budget,
//     plus "+v" asm pins to block rematerialization.
//   k in [384,512): 128 KB XOR-swizzled LDS, shared across threads.
//   h: f16 in LDS, double-buffered; uniform ds_read_b128 broadcast; even/odd
//   accumulator chains (dot2 latency ~5cy vs 4cy issue gap at 2 waves/SIMD).
//   One __syncthreads per step.
// ---------------------------------------------------------------------------

typedef _Float16 f16;
typedef _Float16 half2_t __attribute__((ext_vector_type(2)));
typedef _Float16 half8_t __attribute__((ext_vector_type(8)));
typedef float f32x4 __attribute__((ext_vector_type(4)));
typedef unsigned int u32x4 __attribute__((ext_vector_type(4)));

#define HDIM 512
#define BATCH 64
#define TSTEPS 512
#define OUTC 4

__device__ __forceinline__ float dot2f(unsigned int h, unsigned int w, float acc) {
#if __has_builtin(__builtin_amdgcn_fdot2)
  return __builtin_amdgcn_fdot2(__builtin_bit_cast(half2_t, h),
                                __builtin_bit_cast(half2_t, w), acc, false);
#else
  half2_t a = __builtin_bit_cast(half2_t, h);
  half2_t b = __builtin_bit_cast(half2_t, w);
  return acc + (float)a.x * (float)b.x + (float)a.y * (float)b.y;
#endif
}

// ---- K1: fp32 -> f16 weight conversion -------------------------------------
__global__ void convert_w(const float* __restrict__ Win, const float* __restrict__ Wh,
                          f16* __restrict__ wif, f16* __restrict__ whf) {
  int i = blockIdx.x * 256 + threadIdx.x;
  if (i < HDIM * HDIM) {
    wif[i] = (f16)Win[i];
    whf[i] = (f16)Wh[i];
  }
}

// ---- K1b: gather+convert embeddings once -----------------------------------
__global__ __launch_bounds__(256) void embed_f16(const int* __restrict__ ids,
                                                 const float* __restrict__ emb,
                                                 f16* __restrict__ xh) {
  int gid = blockIdx.x * 256 + threadIdx.x;   // 32768 rows x 128 float4-lanes
  int r = gid >> 7;                           // token row = t*64 + b
  int lane = gid & 127;
  int id = ids[(r & 63) * TSTEPS + (r >> 6)]; // ids[b][t], [B][T] layout
  float4 a = *(const float4*)(emb + id * HDIM + lane * 4);
  half2_t lo, hi;
  lo.x = (f16)a.x; lo.y = (f16)a.y;
  hi.x = (f16)a.z; hi.y = (f16)a.w;
  half2_t* dst = (half2_t*)(xh + r * HDIM + lane * 4);
  dst[0] = lo;
  dst[1] = hi;
}

// ---- K2: pre[t*64+b][j] = xh @ W_in^T + b_h  (MFMA f16) --------------------
__global__ __launch_bounds__(256) void gemm_pre(const f16* __restrict__ xh,
                                                const f16* __restrict__ wif,
                                                const float* __restrict__ bh,
                                                f16* __restrict__ preh) {
  __shared__ __align__(16) f16 Al[64][40];
  __shared__ __align__(16) f16 Bl[64][40];

  const int tid = threadIdx.x;
  const int rb = blockIdx.x;
  const int nb = blockIdx.y;
  const int w = tid >> 6;
  const int l = tid & 63;

  f32x4 acc[4] = {};
  const int srow = tid >> 2;
  const int quad = tid & 3;

  for (int k0 = 0; k0 < HDIM; k0 += 32) {
    *(u32x4*)&Al[srow][quad * 8] =
        *(const u32x4*)(xh + (rb * 64 + srow) * HDIM + k0 + quad * 8);
    *(u32x4*)&Bl[srow][quad * 8] =
        *(const u32x4*)(wif + (nb * 64 + srow) * HDIM + k0 + quad * 8);
    __syncthreads();

    half8_t af = *(const half8_t*)&Al[w * 16 + (l & 15)][(l >> 4) * 8];
#pragma unroll
    for (int nt = 0; nt < 4; ++nt) {
      half8_t bf = *(const half8_t*)&Bl[nt * 16 + (l & 15)][(l >> 4) * 8];
      acc[nt] = __builtin_amdgcn_mfma_f32_16x16x32_f16(af, bf, acc[nt], 0, 0, 0);
    }
    __syncthreads();
  }

  // epilogue: C/D mapping col=lane&15, row=(lane>>4)*4+i  (m89-verified)
#pragma unroll
  for (int nt = 0; nt < 4; ++nt) {
#pragma unroll
    for (int i = 0; i < 4; ++i) {
      int r = rb * 64 + w * 16 + (l >> 4) * 4 + i;
      int c = nb * 64 + nt * 16 + (l & 15);
      preh[r * HDIM + c] = (f16)(acc[nt][i] + bh[c]);
    }
  }
}

// ---- K3: the 512-step recurrence, one batch row per CU ---------------------
// 512 threads (8 waves, 2 waves/EU — pinned), thread j owns output col j.
__global__ __launch_bounds__(512)
__attribute__((amdgpu_waves_per_eu(2, 2)))
void rnn_steps(const f16* __restrict__ preh,
               const f16* __restrict__ whf,
               float* __restrict__ hT) {
  __shared__ __align__(16) u32x4 wlds[HDIM * 16];          // 128 KB: k in [384,512)
  __shared__ __align__(16) unsigned int hb[2][HDIM / 2];   // h as f16 pairs, dbuf

  const int j = threadIdx.x;   // output column
  const int b = blockIdx.x;    // batch row

  // Swizzled LDS weights: row r, 16B granule c stored at (c ^ (r&15)).
  for (int q = 0; q < 16; ++q) {
    int idx = q * 512 + j;          // 8192 granules over 512 rows x 16
    int row = idx >> 4, c = idx & 15;
    u32x4 v = *(const u32x4*)(whf + row * HDIM + 384 + c * 8);
    wlds[row * 16 + (c ^ (row & 15))] = v;
  }

  // Register-resident weights: W_h[j][0:384) = 192 dwords, "+v"-pinned
  // chunk-wise right after each load (blocks remat; bounds peak pressure).
  unsigned int wr[192];
  {
    const u32x4* wrow = (const u32x4*)(whf + j * HDIM);
#pragma unroll
    for (int c = 0; c < 48; ++c) {
      u32x4 v = wrow[c];
      unsigned int x0 = v[0], x1 = v[1], x2 = v[2], x3 = v[3];
      asm volatile("" : "+v"(x0), "+v"(x1), "+v"(x2), "+v"(x3));
      wr[4 * c + 0] = x0; wr[4 * c + 1] = x1;
      wr[4 * c + 2] = x2; wr[4 * c + 3] = x3;
    }
  }

  if (j < HDIM / 2) hb[0][j] = 0u;  // h0 = 0
  __syncthreads();

  float pre_cur = (float)preh[b * HDIM + j];  // t = 0
  const u32x4* wl = &wlds[j * 16];
  const int sw = j & 15;

  for (int t = 0; t < TSTEPS; ++t) {
    // prefetch next step's pre to hide HBM latency under the dot loop
    float pre_next = 0.f;
    if (t < TSTEPS - 1) pre_next = (float)preh[((t + 1) * BATCH + b) * HDIM + j];

    const u32x4* hp = (const u32x4*)hb[t & 1];
    float ae = pre_cur, ao = 0.f;   // even/odd chains: 2 independent dep chains
#pragma unroll
    for (int c = 0; c < 48; c += 2) {   // k in [0,384): register weights
      u32x4 hA = hp[c];                 // uniform-address broadcast read
      ae = dot2f(hA[0], wr[4 * c + 0], ae);
      ae = dot2f(hA[1], wr[4 * c + 1], ae);
      ae = dot2f(hA[2], wr[4 * c + 2], ae);
      ae = dot2f(hA[3], wr[4 * c + 3], ae);
      u32x4 hB = hp[c + 1];
      ao = dot2f(hB[0], wr[4 * c + 4], ao);
      ao = dot2f(hB[1], wr[4 * c + 5], ao);
      ao = dot2f(hB[2], wr[4 * c + 6], ao);
      ao = dot2f(hB[3], wr[4 * c + 7], ao);
    }
#pragma unroll
    for (int c = 0; c < 16; c += 2) {   // k in [384,512): LDS weights
      u32x4 hA = hp[48 + c];
      u32x4 wA = wl[c ^ sw];
      ae = dot2f(hA[0], wA[0], ae);
      ae = dot2f(hA[1], wA[1], ae);
      ae = dot2f(hA[2], wA[2], ae);
      ae = dot2f(hA[3], wA[3], ae);
      u32x4 hB = hp[49 + c];
      u32x4 wB = wl[(c + 1) ^ sw];
      ao = dot2f(hB[0], wB[0], ao);
      ao = dot2f(hB[1], wB[1], ao);
      ao = dot2f(hB[2], wB[2], ao);
      ao = dot2f(hB[3], wB[3], ao);
    }
    float acc = fmaxf(ae + ao, 0.f);
    ((f16*)hb[(t + 1) & 1])[j] = (f16)acc;     // publish h for next step
    if (t == TSTEPS - 1) hT[b * HDIM + j] = acc;
    pre_cur = pre_next;
    __syncthreads();   // one barrier/step
  }
}

// ---- K4: logits + softmax + log_softmax + NLL ------------------------------
__global__ void tail_kernel(const float* __restrict__ hT, const float* __restrict__ Wout,
                            const float* __restrict__ bout, const int* __restrict__ labels,
                            float* __restrict__ out) {
  __shared__ float lred[BATCH];
  const int b = threadIdx.x;  // 64 threads, 1 wave
  const float4* hr = (const float4*)(hT + b * HDIM);
  const float4* w0 = (const float4*)(Wout + 0 * HDIM);
  const float4* w1 = (const float4*)(Wout + 1 * HDIM);
  const float4* w2 = (const float4*)(Wout + 2 * HDIM);
  const float4* w3 = (const float4*)(Wout + 3 * HDIM);
  float z0 = bout[0], z1 = bout[1], z2 = bout[2], z3 = bout[3];
#pragma unroll 4
  for (int k = 0; k < HDIM / 4; ++k) {
    float4 h = hr[k];
    float4 a = w0[k], c = w1[k], d = w2[k], e = w3[k];
    z0 += h.x * a.x + h.y * a.y + h.z * a.z + h.w * a.w;
    z1 += h.x * c.x + h.y * c.y + h.z * c.z + h.w * c.w;
    z2 += h.x * d.x + h.y * d.y + h.z * d.z + h.w * d.w;
    z3 += h.x * e.x + h.y * e.y + h.z * e.z + h.w * e.w;
  }
  float m = fmaxf(fmaxf(z0, z1), fmaxf(z2, z3));
  float e0 = __expf(z0 - m), e1 = __expf(z1 - m), e2 = __expf(z2 - m), e3 = __expf(z3 - m);
  float se = e0 + e1 + e2 + e3;
  float p0 = e0 / se, p1 = e1 / se, p2 = e2 / se, p3 = e3 / se;
  float m2 = fmaxf(fmaxf(p0, p1), fmaxf(p2, p3));
  float s2 = __expf(p0 - m2) + __expf(p1 - m2) + __expf(p2 - m2) + __expf(p3 - m2);
  float lse = m2 + __logf(s2);
  int lab = labels[b];
  float pl = (lab == 0) ? p0 : (lab == 1) ? p1 : (lab == 2) ? p2 : p3;
  lred[b] = pl - lse;
  out[1 + b * 4 + 0] = p0;
  out[1 + b * 4 + 1] = p1;
  out[1 + b * 4 + 2] = p2;
  out[1 + b * 4 + 3] = p3;
  __syncthreads();
  if (b == 0) {
    float s = 0.f;
#pragma unroll
    for (int i = 0; i < BATCH; ++i) s += lred[i];
    out[0] = -s / (float)BATCH;
  }
}

// ---------------------------------------------------------------------------
extern "C" void kernel_launch(void* const* d_in, const int* in_sizes, int n_in,
                              void* d_out, int out_size, void* d_ws, size_t ws_size,
                              hipStream_t stream) {
  const int* ids = (const int*)d_in[0];
  const int* labels = (const int*)d_in[1];
  const float* emb = (const float*)d_in[2];
  const float* Win = (const float*)d_in[3];
  const float* Wh = (const float*)d_in[4];
  const float* bh = (const float*)d_in[5];
  const float* Wout = (const float*)d_in[6];
  const float* bout = (const float*)d_in[7];
  float* out = (float*)d_out;

  // ws layout: whf 512K | wif 512K | preh 32M | xh 32M | hT 128K  (~66 MB)
  char* ws = (char*)d_ws;
  f16* whf = (f16*)ws;
  f16* wif = (f16*)(ws + (512 << 10));
  f16* preh = (f16*)(ws + (1 << 20));
  f16* xh = (f16*)(ws + (1 << 20) + (32 << 20));
  float* hT = (float*)(ws + (1 << 20) + (64 << 20));

  convert_w<<<dim3(1024), dim3(256), 0, stream>>>(Win, Wh, wif, whf);
  embed_f16<<<dim3((BATCH * TSTEPS * 128) / 256), dim3(256), 0, stream>>>(ids, emb, xh);
  gemm_pre<<<dim3(512, 8), dim3(256), 0, stream>>>(xh, wif, bh, preh);
  rnn_steps<<<dim3(64), dim3(512), 0, stream>>>(preh, whf, hT);
  tail_kernel<<<dim3(1), dim3(64), 0, stream>>>(hT, Wout, bout, labels, out);
}